// Round 2
// baseline (2638.528 us; speedup 1.0000x reference)
//
#include <hip/hip_runtime.h>
#include <hip/hip_bf16.h>

// LSTMReg on MI355X — round 2: MFMA recurrence, bf16 hi/lo 3-pass.
// NB=16 chains/block (=MFMA N-tile), 32 blocks, 4 waves/block.
// Wave w owns row-tiles {w,4+w,8+w,12+w} (one per gate) so each lane holds
// z_i,z_f,z_g,z_o for the same (h,b) -> gates fully in-register.
// W fragments (hi+lo) live in VGPRs (128 regs); per-step LDS = 4 b128 reads.
// Layer0 emits h1 in B-fragment order (bf16 hi/lo) to d_ws; layer1 consumes
// it directly as its x-fragments. One barrier/step (double-buffered h).

typedef short bf16x8 __attribute__((ext_vector_type(8)));
typedef short bf16x4 __attribute__((ext_vector_type(4)));
typedef float f32x4  __attribute__((ext_vector_type(4)));

#define MFMA16(A, B, C) __builtin_amdgcn_mfma_f32_16x16x32_bf16(A, B, C, 0, 0, 0)

constexpr int T_LEN = 1024;
constexpr int H     = 64;
constexpr int B_TOT = 512;
constexpr int NB    = 16;              // chains per block
constexpr int NTHR  = 256;             // 4 waves
constexpr int NBLK  = B_TOT / NB;      // 32
// xf (fragment buffer) layout per block: [t][which(hi/lo)][b(16)][f(64)] bf16
constexpr int    XF_T_STRIDE = 2 * NB * H;                 // 2048 shorts per t
constexpr size_t XF_BLK_SHORTS = (size_t)T_LEN * XF_T_STRIDE;  // 2 Mi shorts = 4 MiB

__device__ __forceinline__ short f2bf(float f) {
  unsigned u = __builtin_bit_cast(unsigned, f);
  unsigned r = (u + 0x7fffu + ((u >> 16) & 1u)) >> 16;  // RNE
  return (short)r;
}
__device__ __forceinline__ float bf2f(short s) {
  unsigned u = ((unsigned)(unsigned short)s) << 16;
  return __builtin_bit_cast(float, u);
}
__device__ __forceinline__ float sigm(float x) { return 1.0f / (1.0f + __expf(-x)); }
__device__ __forceinline__ float tanhf_(float x) { return 1.0f - 2.0f / (1.0f + __expf(2.0f * x)); }

template <bool IS_L0>
__global__ __launch_bounds__(NTHR, 1) void lstm_mfma(
    const float* __restrict__ xin,    // L0: x [B][T][64] fp32
    const short* __restrict__ xf_in,  // L1: fragment buffer (from L0)
    short* __restrict__ xf_out,       // L0: fragment buffer out
    const float* __restrict__ w_ih,   // [256][64]
    const float* __restrict__ w_hh,   // [256][64]
    const float* __restrict__ b_ih,
    const float* __restrict__ b_hh,
    const float* __restrict__ fc_w,   // L1: [64]
    const float* __restrict__ fc_b,   // L1: [1]
    float* __restrict__ out,          // L1: [B]
    int chain_base)                   // global chain index of block 0 of this launch
{
  const int tid = threadIdx.x;
  const int w   = tid >> 6;          // wave 0..3 (row-subtile)
  const int l   = tid & 63;
  const int b   = l & 15;            // chain / N-col / A-row-local
  const int lq  = l >> 4;            // 0..3 k-quarter
  const int blk = blockIdx.x;        // chunk-local
  const int chain0 = chain_base + blk * NB;

  __shared__ __align__(16) short hbuf[2][2][NB][72];  // [buf][hi/lo][b][h(+pad)]
  __shared__ float hfin[NB][H];                       // L1 epilogue

  for (int i = tid; i < 2 * 2 * NB * 72; i += NTHR) ((short*)hbuf)[i] = 0;

  // ---- one-time: gather W fragments into VGPRs (hi/lo split) ----
  // A-frag (16x32): row = l&15 (tile-local), k = 32*kt + 8*lq + e.
  bf16x8 whi[4][4], wlo[4][4];  // [gate][kt]
#pragma unroll
  for (int g = 0; g < 4; ++g) {
#pragma unroll
    for (int kt = 0; kt < 4; ++kt) {
      const int row = 64 * g + 16 * w + b;
      const int k0  = 32 * kt + 8 * lq;
      const float* src = (k0 < 64) ? &w_ih[row * 64 + k0] : &w_hh[row * 64 + (k0 - 64)];
      float4 v0 = *reinterpret_cast<const float4*>(src);
      float4 v1 = *reinterpret_cast<const float4*>(src + 4);
      float vv[8] = {v0.x, v0.y, v0.z, v0.w, v1.x, v1.y, v1.z, v1.w};
      bf16x8 hi8, lo8;
#pragma unroll
      for (int e = 0; e < 8; ++e) {
        short hh = f2bf(vv[e]);
        hi8[e] = hh;
        lo8[e] = f2bf(vv[e] - bf2f(hh));
      }
      whi[g][kt] = hi8;
      wlo[g][kt] = lo8;
    }
  }

  // bias fragments (match D layout: row_local = 4*lq + r)
  f32x4 biasf[4];
#pragma unroll
  for (int g = 0; g < 4; ++g) {
#pragma unroll
    for (int r = 0; r < 4; ++r) {
      int row = 64 * g + 16 * w + 4 * lq + r;
      biasf[g][r] = b_ih[row] + b_hh[row];
    }
  }

  // ---- input prefetch state (t=0) ----
  const float* xptr = nullptr;
  const short* xf_rd = nullptr;
  float4 xf32[4];   // L0: 16 fp32 (f = 8lq..+7 and 32+8lq..+7)
  bf16x8 xbf[4];    // L1: kt0hi, kt0lo, kt1hi, kt1lo
  if constexpr (IS_L0) {
    xptr = xin + (size_t)(chain0 + b) * T_LEN * H + 8 * lq;
    xf32[0] = *reinterpret_cast<const float4*>(xptr);
    xf32[1] = *reinterpret_cast<const float4*>(xptr + 4);
    xf32[2] = *reinterpret_cast<const float4*>(xptr + 32);
    xf32[3] = *reinterpret_cast<const float4*>(xptr + 36);
  } else {
    xf_rd = xf_in + (size_t)blk * XF_BLK_SHORTS + b * H;
    xbf[0] = *reinterpret_cast<const bf16x8*>(xf_rd + 0 * NB * H + 8 * lq);
    xbf[1] = *reinterpret_cast<const bf16x8*>(xf_rd + 1 * NB * H + 8 * lq);
    xbf[2] = *reinterpret_cast<const bf16x8*>(xf_rd + 0 * NB * H + 32 + 8 * lq);
    xbf[3] = *reinterpret_cast<const bf16x8*>(xf_rd + 1 * NB * H + 32 + 8 * lq);
  }
  short* xf_wr = nullptr;
  if constexpr (IS_L0) xf_wr = xf_out + (size_t)blk * XF_BLK_SHORTS + b * H + 16 * w + 4 * lq;

  __syncthreads();

  f32x4 creg = {0.f, 0.f, 0.f, 0.f};
  const int hoff = 16 * w + 4 * lq;  // h indices this lane produces (hoff..hoff+3)

  for (int t = 0; t < T_LEN; ++t) {
    const int cur = t & 1, nxt = cur ^ 1;

    // current-step x fragments
    bf16x8 xk0h, xk0l, xk1h, xk1l;
    if constexpr (IS_L0) {
      float vv[16] = {xf32[0].x, xf32[0].y, xf32[0].z, xf32[0].w,
                      xf32[1].x, xf32[1].y, xf32[1].z, xf32[1].w,
                      xf32[2].x, xf32[2].y, xf32[2].z, xf32[2].w,
                      xf32[3].x, xf32[3].y, xf32[3].z, xf32[3].w};
#pragma unroll
      for (int e = 0; e < 8; ++e) {
        short hh = f2bf(vv[e]);
        xk0h[e] = hh;
        xk0l[e] = f2bf(vv[e] - bf2f(hh));
        short h2 = f2bf(vv[8 + e]);
        xk1h[e] = h2;
        xk1l[e] = f2bf(vv[8 + e] - bf2f(h2));
      }
    } else {
      xk0h = xbf[0]; xk0l = xbf[1]; xk1h = xbf[2]; xk1l = xbf[3];
    }

    // prefetch t+1 input (hidden under MFMA + gates)
    if (t + 1 < T_LEN) {
      if constexpr (IS_L0) {
        const float* p = xptr + (size_t)(t + 1) * H;
        xf32[0] = *reinterpret_cast<const float4*>(p);
        xf32[1] = *reinterpret_cast<const float4*>(p + 4);
        xf32[2] = *reinterpret_cast<const float4*>(p + 32);
        xf32[3] = *reinterpret_cast<const float4*>(p + 36);
      } else {
        const short* p = xf_rd + (size_t)(t + 1) * XF_T_STRIDE;
        xbf[0] = *reinterpret_cast<const bf16x8*>(p + 0 * NB * H + 8 * lq);
        xbf[1] = *reinterpret_cast<const bf16x8*>(p + 1 * NB * H + 8 * lq);
        xbf[2] = *reinterpret_cast<const bf16x8*>(p + 0 * NB * H + 32 + 8 * lq);
        xbf[3] = *reinterpret_cast<const bf16x8*>(p + 1 * NB * H + 32 + 8 * lq);
      }
    }

    // h fragments from LDS (k = 64 + 8lq + e -> h_idx = 8lq+e | 32+8lq+e)
    const short* hb = &hbuf[cur][0][b][0];
    const short* lb = &hbuf[cur][1][b][0];
    bf16x8 hk2h = *reinterpret_cast<const bf16x8*>(hb + 8 * lq);
    bf16x8 hk3h = *reinterpret_cast<const bf16x8*>(hb + 32 + 8 * lq);
    bf16x8 hk2l = *reinterpret_cast<const bf16x8*>(lb + 8 * lq);
    bf16x8 hk3l = *reinterpret_cast<const bf16x8*>(lb + 32 + 8 * lq);

    // ---- 48 MFMAs: z = bias + W*[x;h], 3-pass hi/lo ----
    f32x4 a0 = biasf[0], a1 = biasf[1], a2 = biasf[2], a3 = biasf[3];
#define PASS(W0, W1, W2, W3, BB)      \
  a0 = MFMA16(W0, BB, a0);            \
  a1 = MFMA16(W1, BB, a1);            \
  a2 = MFMA16(W2, BB, a2);            \
  a3 = MFMA16(W3, BB, a3);
    PASS(whi[0][0], whi[1][0], whi[2][0], whi[3][0], xk0h)
    PASS(whi[0][0], whi[1][0], whi[2][0], whi[3][0], xk0l)
    PASS(wlo[0][0], wlo[1][0], wlo[2][0], wlo[3][0], xk0h)
    PASS(whi[0][1], whi[1][1], whi[2][1], whi[3][1], xk1h)
    PASS(whi[0][1], whi[1][1], whi[2][1], whi[3][1], xk1l)
    PASS(wlo[0][1], wlo[1][1], wlo[2][1], wlo[3][1], xk1h)
    PASS(whi[0][2], whi[1][2], whi[2][2], whi[3][2], hk2h)
    PASS(whi[0][2], whi[1][2], whi[2][2], whi[3][2], hk2l)
    PASS(wlo[0][2], wlo[1][2], wlo[2][2], wlo[3][2], hk2h)
    PASS(whi[0][3], whi[1][3], whi[2][3], whi[3][3], hk3h)
    PASS(whi[0][3], whi[1][3], whi[2][3], whi[3][3], hk3l)
    PASS(wlo[0][3], wlo[1][3], wlo[2][3], wlo[3][3], hk3h)
#undef PASS

    // ---- gates, fully in-register (torch order i,f,g,o) ----
    f32x4 hnew;
#pragma unroll
    for (int r = 0; r < 4; ++r) {
      float ig = sigm(a0[r]);
      float fg = sigm(a1[r]);
      float gg = tanhf_(a2[r]);
      float og = sigm(a3[r]);
      float c  = fg * creg[r] + ig * gg;
      creg[r]  = c;
      hnew[r]  = og * tanhf_(c);
    }
    bf16x4 h4, l4;
#pragma unroll
    for (int r = 0; r < 4; ++r) {
      short hh = f2bf(hnew[r]);
      h4[r] = hh;
      l4[r] = f2bf(hnew[r] - bf2f(hh));
    }
    *reinterpret_cast<bf16x4*>(&hbuf[nxt][0][b][hoff]) = h4;
    *reinterpret_cast<bf16x4*>(&hbuf[nxt][1][b][hoff]) = l4;
    if constexpr (IS_L0) {
      short* wp = xf_wr + (size_t)t * XF_T_STRIDE;
      *reinterpret_cast<bf16x4*>(wp) = h4;
      *reinterpret_cast<bf16x4*>(wp + NB * H) = l4;
    } else {
      if (t == T_LEN - 1) {
#pragma unroll
        for (int r = 0; r < 4; ++r) hfin[b][hoff + r] = hnew[r];
      }
    }
    __syncthreads();
  }

  // ---- L1 epilogue: FC(64->1) on last h ----
  if constexpr (!IS_L0) {
    if (tid < NB) {
      float acc = fc_b[0];
#pragma unroll
      for (int h = 0; h < H; ++h) acc += fc_w[h] * hfin[tid][h];
      out[chain0 + tid] = acc;
    }
  }
}

extern "C" void kernel_launch(void* const* d_in, const int* in_sizes, int n_in,
                              void* d_out, int out_size, void* d_ws, size_t ws_size,
                              hipStream_t stream) {
  const float* x     = (const float*)d_in[0];
  const float* w_ih0 = (const float*)d_in[1];
  const float* w_hh0 = (const float*)d_in[2];
  const float* b_ih0 = (const float*)d_in[3];
  const float* b_hh0 = (const float*)d_in[4];
  const float* w_ih1 = (const float*)d_in[5];
  const float* w_hh1 = (const float*)d_in[6];
  const float* b_ih1 = (const float*)d_in[7];
  const float* b_hh1 = (const float*)d_in[8];
  const float* fc_w  = (const float*)d_in[9];
  const float* fc_b  = (const float*)d_in[10];
  float* out = (float*)d_out;

  short* xf = (short*)d_ws;
  const size_t blk_bytes = XF_BLK_SHORTS * sizeof(short);  // 4 MiB per block
  int max_blk = (int)(ws_size / blk_bytes);
  if (max_blk > NBLK) max_blk = NBLK;
  if (max_blk < 1) max_blk = 1;  // ws assumed >= 4 MiB

  for (int cb = 0; cb < NBLK; cb += max_blk) {
    int nb = NBLK - cb < max_blk ? NBLK - cb : max_blk;
    lstm_mfma<true><<<dim3(nb), dim3(NTHR), 0, stream>>>(
        x, (const short*)nullptr, xf, w_ih0, w_hh0, b_ih0, b_hh0,
        (const float*)nullptr, (const float*)nullptr, (float*)nullptr, cb * NB);
    lstm_mfma<false><<<dim3(nb), dim3(NTHR), 0, stream>>>(
        (const float*)nullptr, xf, (short*)nullptr, w_ih1, w_hh1, b_ih1, b_hh1,
        fc_w, fc_b, out, cb * NB);
  }
}